// Round 3
// baseline (299.293 us; speedup 1.0000x reference)
//
#include <hip/hip_runtime.h>
#include <hip/hip_bf16.h>
#include <hip/hip_fp8.h>

#define N_NODES 50000
#define N_EDGES 1600000
#define N_GRAPHS 64
#define D_IN 128
#define D_H 512
#define D_OUT 16

// atomic-free CSR build: buckets of 128 rows, 391 blocks for both phases
#define NBUK 391                      // ceil(50000/128)
#define BUK_CAP 4608                  // mean 4092 + ~8 sigma
#define P1_EDGES 4096                 // edges per partition block
#define P1_BLOCKS ((N_EDGES + P1_EDGES - 1) / P1_EDGES)   // 391

#define MSPLIT 8                      // M-tile interleave factor for the GEMM
#define HALF_COL 25000                // col-range split: 3.2MB source slice fits 4MB XCD L2

typedef short bf16x8 __attribute__((ext_vector_type(8)));
typedef float f32x4 __attribute__((ext_vector_type(4)));

static __device__ __forceinline__ unsigned short f2bf(float f) {
    __hip_bfloat16 h = __float2bfloat16(f);   // RNE
    return *(unsigned short*)&h;
}

static __device__ __forceinline__ float2 fp8x2_dec(unsigned short u) {
    __hip_fp8x2_e4m3 p;
    p.__x = (__hip_fp8x2_storage_t)u;
    return static_cast<float2>(p);
}

static __device__ __forceinline__ unsigned short fp8x2_enc(float a, float b) {
    __hip_fp8_e4m3 pa(a), pb(b);
    return (unsigned short)((unsigned)pa.__x | ((unsigned)pb.__x << 8));
}

// decode 16 fp8 (one uint4 = 16B slice) and accumulate into acc[16]
static __device__ __forceinline__ void dec16_add(uint4 u, float* acc) {
    unsigned vv[4] = {u.x, u.y, u.z, u.w};
#pragma unroll
    for (int w = 0; w < 4; ++w) {
        float2 a = fp8x2_dec((unsigned short)(vv[w] & 0xFFFFu));
        float2 b = fp8x2_dec((unsigned short)(vv[w] >> 16));
        acc[w * 4 + 0] += a.x; acc[w * 4 + 1] += a.y;
        acc[w * 4 + 2] += b.x; acc[w * 4 + 3] += b.y;
    }
}

// ---------------------------------------------------------------- CSR build (atomic-free)
// P1: 391 blocks x 512 threads, 4096 edges each. rec = (buk:9)<<23 | (rlow:7)<<16 | col:16.

__global__ __launch_bounds__(512) void partition_edges(const int* __restrict__ row,
                                                       const int* __restrict__ col,
                                                       int* __restrict__ bucket_cnt,
                                                       unsigned* __restrict__ edge_buf) {
    __shared__ unsigned recs[P1_EDGES];     // 16 KB
    __shared__ unsigned sorted[P1_EDGES];   // 16 KB
    __shared__ int hist4[4][NBUK];          // per-wave-pair counts -> local bases
    __shared__ int cur4[4][NBUK];
    __shared__ int gbase[NBUK];
    __shared__ int scan[512];
    int tid = threadIdx.x;
    int w2 = tid >> 7;                      // wave-pair 0..3
    int e0 = blockIdx.x * P1_EDGES;
    int m = N_EDGES - e0; if (m > P1_EDGES) m = P1_EDGES;

    for (int i = tid; i < 4 * NBUK; i += 512) ((int*)hist4)[i] = 0;
    for (int i = tid; i < 4 * NBUK; i += 512) ((int*)cur4)[i] = 0;
    __syncthreads();
    for (int i = tid; i < m; i += 512) {
        int r = row[e0 + i];
        int c = col[e0 + i];
        int buk = r >> 7;
        recs[i] = ((unsigned)buk << 23) | ((unsigned)(r & 127) << 16) | (unsigned)c;
        atomicAdd(&hist4[w2][buk], 1);
    }
    __syncthreads();
    int tot = 0;
    if (tid < NBUK) tot = hist4[0][tid] + hist4[1][tid] + hist4[2][tid] + hist4[3][tid];
    scan[tid] = (tid < NBUK) ? tot : 0;
    __syncthreads();
    for (int off = 1; off < 512; off <<= 1) {
        int v = (tid >= off) ? scan[tid - off] : 0;
        __syncthreads();
        scan[tid] += v;
        __syncthreads();
    }
    if (tid < NBUK) {
        int run = (tid == 0) ? 0 : scan[tid - 1];   // block-local excl base
        gbase[tid] = (tot > 0) ? atomicAdd(&bucket_cnt[tid], tot) : 0;  // reserve range
#pragma unroll
        for (int w = 0; w < 4; ++w) {               // per-sub-group local bases
            int c = hist4[w][tid];
            hist4[w][tid] = run;
            run += c;
        }
    }
    __syncthreads();
    for (int i = tid; i < m; i += 512) {            // rank + reorder (bucket-major)
        unsigned rec = recs[i];
        int buk = rec >> 23;
        int rank = atomicAdd(&cur4[w2][buk], 1);
        sorted[hist4[w2][buk] + rank] = rec;
    }
    __syncthreads();
    for (int p = tid; p < m; p += 512) {            // coalesced-run writes
        unsigned rec = sorted[p];
        int buk = rec >> 23;
        edge_buf[(size_t)buk * BUK_CAP + gbase[buk] + (p - hist4[0][buk])] = rec;
    }
}

// P2: one block per bucket (391 x 512); inline scan of bucket_cnt; LDS-cursor scatter.
// NOW also splits each row's edge list into [low cols | high cols] and emits rowmid.
__global__ __launch_bounds__(512) void finalize_csr(const unsigned* __restrict__ edge_buf,
                                                    const int* __restrict__ bucket_cnt,
                                                    int* __restrict__ rowptr,
                                                    int* __restrict__ rowmid,
                                                    float* __restrict__ invdeg,
                                                    unsigned short* __restrict__ csr_col) {
    __shared__ int hist[128], hist_lo[128], excl[128], cur_lo[128], cur_hi[128];
    __shared__ int scan[512];
    int b = blockIdx.x;
    int tid = threadIdx.x;
    scan[tid] = (tid < NBUK) ? bucket_cnt[tid] : 0;
    __syncthreads();
    for (int off = 1; off < 512; off <<= 1) {
        int v = (tid >= off) ? scan[tid - off] : 0;
        __syncthreads();
        scan[tid] += v;
        __syncthreads();
    }
    int cnt = bucket_cnt[b];
    int base = (b == 0) ? 0 : scan[b - 1];
    const unsigned* src = edge_buf + (size_t)b * BUK_CAP;
    __syncthreads();
    if (tid < 128) { hist[tid] = 0; hist_lo[tid] = 0; cur_lo[tid] = 0; cur_hi[tid] = 0; }
    __syncthreads();
    for (int i = tid; i < cnt; i += 512) {
        unsigned rec = src[i];
        int rl = (rec >> 16) & 127;
        atomicAdd(&hist[rl], 1);
        if ((rec & 0xFFFFu) < HALF_COL) atomicAdd(&hist_lo[rl], 1);
    }
    __syncthreads();
    scan[tid] = (tid < 128) ? hist[tid] : 0;
    __syncthreads();
    for (int off = 1; off < 512; off <<= 1) {
        int v = (tid >= off) ? scan[tid - off] : 0;
        __syncthreads();
        scan[tid] += v;
        __syncthreads();
    }
    if (tid < 128) excl[tid] = (tid == 0) ? 0 : scan[tid - 1];
    __syncthreads();
    int r = b * 128 + tid;
    if (tid < 128 && r < N_NODES) {
        rowptr[r] = base + excl[tid];
        rowmid[r] = base + excl[tid] + hist_lo[tid];
        invdeg[r] = 1.0f / (float)(hist[tid] + 1);   // +1: self loop
    }
    if (b == NBUK - 1 && tid == 0) rowptr[N_NODES] = base + cnt;
    for (int i = tid; i < cnt; i += 512) {
        unsigned rec = src[i];
        int rl = (rec >> 16) & 127;
        bool lo = (rec & 0xFFFFu) < HALF_COL;
        int pos = lo ? excl[rl] + atomicAdd(&cur_lo[rl], 1)
                     : excl[rl] + hist_lo[rl] + atomicAdd(&cur_hi[rl], 1);
        csr_col[base + pos] = (unsigned short)(rec & 0xFFFFu);
    }
}

// ---------------------------------------------------------------- merged prep
// [0,12500): convert_x; [12500,12756): make_w1p; [12756,12790): fold_w + graph bounds
// + zero-row sentinels for the gather (row N_NODES of xf/h0f/h1f).

__global__ __launch_bounds__(256) void prep(const float* __restrict__ x,
                                            unsigned short* __restrict__ xf,
                                            const float* __restrict__ w1,
                                            unsigned short* __restrict__ w1p,
                                            const float* __restrict__ w2,
                                            const float* __restrict__ wc,
                                            const float* __restrict__ b2,
                                            const float* __restrict__ bc,
                                            const int* __restrict__ batch,
                                            float* __restrict__ wcomb,
                                            float* __restrict__ bcomb,
                                            int* __restrict__ gcnt,
                                            int* __restrict__ gstart,
                                            unsigned short* __restrict__ h0f,
                                            unsigned short* __restrict__ h1f) {
    int b = blockIdx.x;
    int tid = threadIdx.x;
    if (b < 12500) {                                // convert_x: 12500*256 == N*64 exactly
        int i = b * 256 + tid;
        float2 v = ((const float2*)x)[i];
        xf[i] = fp8x2_enc(v.x, v.y);
        return;
    }
    if (b < 12756) {                                // make_w1p: 256 blocks, 65536 elems
        int i = (b - 12500) * 256 + tid;
        int j = i & 7, lane = (i >> 3) & 63, s = (i >> 9) & 3, t = i >> 11;
        int k = s * 32 + (lane >> 4) * 8 + j;
        int n = t * 16 + (lane & 15);
        w1p[i] = f2bf(w1[(size_t)k * D_H + n]);
        return;
    }
    int fb = b - 12756;                             // fold_w blocks 0..33
    if (fb == 33) {
        if (tid < N_GRAPHS) {
            int g = tid;
            int lo = 0, hi = N_NODES;
            while (lo < hi) { int mid = (lo + hi) >> 1; if (batch[mid] < g) lo = mid + 1; else hi = mid; }
            int a = lo;
            lo = 0; hi = N_NODES;
            while (lo < hi) { int mid = (lo + hi) >> 1; if (batch[mid] < g + 1) lo = mid + 1; else hi = mid; }
            gcnt[g] = lo - a;
            gstart[g] = a;
            if (g == N_GRAPHS - 1) gstart[N_GRAPHS] = N_NODES;
        } else if (tid >= 64 && tid < 256) {        // zero-row sentinels (3 bufs x 64 u16)
            int t = tid - 64;
            unsigned short* bp = (t < 64) ? xf : (t < 128 ? h0f : h1f);
            bp[(size_t)N_NODES * 64 + (t & 63)] = 0;
        }
        return;
    }
    int o = tid & 15, kl = tid >> 4;
    int k = fb * 16 + kl;
    if (k > D_H) return;
    const float* wr = (k < D_H) ? (w2 + (size_t)k * D_H) : b2;
    float s = 0.f;
    for (int j = 0; j < D_H; j += 4) {
        s += wr[j + 0] * wc[(j + 0) * D_OUT + o]
           + wr[j + 1] * wc[(j + 1) * D_OUT + o]
           + wr[j + 2] * wc[(j + 2) * D_OUT + o]
           + wr[j + 3] * wc[(j + 3) * D_OUT + o];
    }
    if (k < D_H) wcomb[k * D_OUT + o] = s;
    else         bcomb[o] = s + bc[o];
}

// ---------------------------------------------------------------- propagation (fp8 storage, f32 accumulate)
// COL-SPLIT: each hop runs in two phases over column ranges [0,25000) and
// [25000,50000). The gathered source slice per phase is 3.2MB and fits a 4MB
// per-XCD L2 (whole 6.4MB table thrashes it; misses hit Infinity-Cache random
// line reads at ~2TB/s -- the measured ~5TB/s effective gather ceiling).
// Phase 0 parks raw f32 sums in accf via non-temporal stores (no L2 pollution);
// phase 1 adds the rest + self loop, scales, emits fp8/bf16. Index streams are
// non-temporal loads so L2 stays reserved for the gather table.
// Shape per phase: 8 rows/wave, 16B/lane (1KB per gather instr), zero-row
// sentinel at N_NODES absorbs degree divergence.

__global__ __launch_bounds__(256) void propagate_half(const unsigned short* __restrict__ xin,
                                                      float* __restrict__ accf,
                                                      unsigned short* __restrict__ out8,
                                                      unsigned* __restrict__ out16,
                                                      int phase, int last, float extra,
                                                      const int* __restrict__ rowptr,
                                                      const int* __restrict__ rowmid,
                                                      const unsigned short* __restrict__ csr_col,
                                                      const float* __restrict__ invdeg) {
    int lane = threadIdx.x & 63;
    int wave = threadIdx.x >> 6;
    int l8   = lane & 7;                 // 16B slice within the row (features 16*l8..16*l8+15)
    int grp  = lane >> 3;                // row-in-wave 0..7
    int r = blockIdx.x * 32 + wave * 8 + grp;
    bool rv = (r < N_NODES);
    int rc = rv ? r : 0;
    int beg = phase ? rowmid[rc] : rowptr[rc];
    int end = phase ? rowptr[rc + 1] : rowmid[rc];
    int nn = rv ? (end - beg) : 0;

    // wave-max degree (all groups iterate together; idle groups read the zero row)
    int nmax = nn;
    { int t = __shfl_xor(nmax, 8, 64);  nmax = t > nmax ? t : nmax; }
    { int t = __shfl_xor(nmax, 16, 64); nmax = t > nmax ? t : nmax; }
    { int t = __shfl_xor(nmax, 32, 64); nmax = t > nmax ? t : nmax; }

    float acc[16];
#pragma unroll
    for (int i = 0; i < 16; ++i) acc[i] = 0.f;

    // self loop in the phase whose col-range contains r (keeps gather slice local)
    if (rv && ((r < HALF_COL) == (phase == 0))) {
        uint4 u = *(const uint4*)(xin + (size_t)r * 64 + l8 * 8);
        dec16_add(u, acc);
    }
    if (phase) {                          // fold in phase-0 partial sums (nt: bypass L2)
        const f32x4* ap = (const f32x4*)(accf + (size_t)rc * 128 + l8 * 16);
#pragma unroll
        for (int i = 0; i < 4; ++i) {
            f32x4 v = __builtin_nontemporal_load(ap + i);
            acc[i * 4 + 0] += v.x; acc[i * 4 + 1] += v.y;
            acc[i * 4 + 2] += v.z; acc[i * 4 + 3] += v.w;
        }
    }

    int base = lane & 56;
    // first batch of 8 column indices: lane l8 holds col (myrow, jb + l8)
    int cv;
    {
        int jj = l8;
        int idx = (jj < nn) ? beg + jj : 0;
        unsigned short cl = __builtin_nontemporal_load(&csr_col[idx]);
        cv = (jj < nn) ? (int)cl : N_NODES;
    }
    for (int jb = 0; jb < nmax; jb += 8) {
        uint4 u[8];
#pragma unroll
        for (int q = 0; q < 8; ++q) {
            int c = __shfl(cv, base + q, 64);
            u[q] = *(const uint4*)(xin + (size_t)c * 64 + l8 * 8);
        }
        // prefetch next batch's column indices while gathers are in flight
        int jn = jb + 8 + l8;
        int idxn = (jn < nn) ? beg + jn : 0;
        unsigned short cln = __builtin_nontemporal_load(&csr_col[idxn]);
        int cvn = (jn < nn) ? (int)cln : N_NODES;
#pragma unroll
        for (int q = 0; q < 8; ++q) dec16_add(u[q], acc);
        cv = cvn;
    }

    if (!rv) return;

    if (phase == 0) {                     // park raw sums (nt store: no L2 pollution)
        f32x4* ap = (f32x4*)(accf + (size_t)r * 128 + l8 * 16);
#pragma unroll
        for (int i = 0; i < 4; ++i) {
            f32x4 v;
            v.x = acc[i * 4 + 0]; v.y = acc[i * 4 + 1];
            v.z = acc[i * 4 + 2]; v.w = acc[i * 4 + 3];
            __builtin_nontemporal_store(v, ap + i);
        }
        return;
    }

    float s = invdeg[r] * extra;
#pragma unroll
    for (int i = 0; i < 16; ++i) acc[i] *= s;

    if (last) {
        uint4 w0, w1v;
        w0.x = (unsigned)f2bf(acc[0])  | ((unsigned)f2bf(acc[1])  << 16);
        w0.y = (unsigned)f2bf(acc[2])  | ((unsigned)f2bf(acc[3])  << 16);
        w0.z = (unsigned)f2bf(acc[4])  | ((unsigned)f2bf(acc[5])  << 16);
        w0.w = (unsigned)f2bf(acc[6])  | ((unsigned)f2bf(acc[7])  << 16);
        w1v.x = (unsigned)f2bf(acc[8])  | ((unsigned)f2bf(acc[9])  << 16);
        w1v.y = (unsigned)f2bf(acc[10]) | ((unsigned)f2bf(acc[11]) << 16);
        w1v.z = (unsigned)f2bf(acc[12]) | ((unsigned)f2bf(acc[13]) << 16);
        w1v.w = (unsigned)f2bf(acc[14]) | ((unsigned)f2bf(acc[15]) << 16);
        unsigned* dst = out16 + (size_t)r * 64 + l8 * 8;
        *(uint4*)dst = w0;
        *(uint4*)(dst + 4) = w1v;
    } else {
        uint4 w;
        w.x = (unsigned)fp8x2_enc(acc[0],  acc[1])  | ((unsigned)fp8x2_enc(acc[2],  acc[3])  << 16);
        w.y = (unsigned)fp8x2_enc(acc[4],  acc[5])  | ((unsigned)fp8x2_enc(acc[6],  acc[7])  << 16);
        w.z = (unsigned)fp8x2_enc(acc[8],  acc[9])  | ((unsigned)fp8x2_enc(acc[10], acc[11]) << 16);
        w.w = (unsigned)fp8x2_enc(acc[12], acc[13]) | ((unsigned)fp8x2_enc(acc[14], acc[15]) << 16);
        *(uint4*)(out8 + (size_t)r * 64 + l8 * 8) = w;
    }
}

// ---------------------------------------------------------------- MFMA GEMM + pool, register-only epilogue
// grid (64 graphs, 4 col-groups, MSPLIT) = 2048 blocks (8/CU). Pool sum computed
// straight from the MFMA C-layout: lane (col=l15, quad) holds rows quad*4+rg of the
// wave's 16-row strip -> per-lane reg sum + shfl_xor(16,32). No per-tile barriers,
// no 34KB LDS tile (only 2KB cross-wave buffer). Zero atomics.

__global__ __launch_bounds__(256) void gemm_graph_pool(const unsigned short* __restrict__ h3b,
                                                       const unsigned short* __restrict__ w1p,
                                                       const float* __restrict__ b1,
                                                       const int* __restrict__ gstart,
                                                       float* __restrict__ gsum) {
    __shared__ float wsum[4][128];
    int tid = threadIdx.x;
    int lane = tid & 63, wave = tid >> 6;
    int quad = lane >> 4, l15 = lane & 15;
    int g = blockIdx.x;
    int nbase = blockIdx.y * 128;
    int ms = blockIdx.z;
    int r0 = gstart[g], r1 = gstart[g + 1];

    float b1v[8];
#pragma unroll
    for (int t = 0; t < 8; ++t) b1v[t] = b1[nbase + t * 16 + l15];

    const unsigned short* bbase = w1p + ((size_t)(blockIdx.y * 8) * 4 * 64 + lane) * 8;

    float gaccT[8];
#pragma unroll
    for (int t = 0; t < 8; ++t) gaccT[t] = 0.f;

    for (int mbase = r0 + ms * 64; mbase < r1; mbase += 64 * MSPLIT) {
        int m = mbase + wave * 16 + l15;
        int mc = m < N_NODES ? m : N_NODES - 1;      // clamp; invalid rows masked below
        const unsigned short* arow = h3b + (size_t)mc * 128 + quad * 8;
        bf16x8 afrag[4];
#pragma unroll
        for (int s = 0; s < 4; ++s)
            afrag[s] = *(const bf16x8*)(arow + s * 32);

        int rowbase = mbase + wave * 16 + quad * 4;  // this lane's C rows: rowbase+rg
#pragma unroll
        for (int t = 0; t < 8; ++t) {
            f32x4 acc = (f32x4){0.f, 0.f, 0.f, 0.f};
#pragma unroll
            for (int s = 0; s < 4; ++s) {
                bf16x8 bfrag = *(const bf16x8*)(bbase + (size_t)(t * 4 + s) * 64 * 8);
                acc = __builtin_amdgcn_mfma_f32_16x16x32_bf16(afrag[s], bfrag, acc, 0, 0, 0);
            }
#pragma unroll
            for (int rg = 0; rg < 4; ++rg) {
                float v = acc[rg] + b1v[t];
                v = v > 0.f ? v : 0.f;
                gaccT[t] += (rowbase + rg < r1) ? v : 0.f;
            }
        }
    }
    // sum the 4 quads (rows 0..15 of the wave strip) per column
#pragma unroll
    for (int t = 0; t < 8; ++t) {
        gaccT[t] += __shfl_xor(gaccT[t], 16, 64);
        gaccT[t] += __shfl_xor(gaccT[t], 32, 64);
    }
    if (quad == 0) {
#pragma unroll
        for (int t = 0; t < 8; ++t)
            wsum[wave][t * 16 + l15] = gaccT[t];
    }
    __syncthreads();
    if (tid < 128)
        gsum[((size_t)ms * N_GRAPHS + g) * D_H + nbase + tid] =
            wsum[0][tid] + wsum[1][tid] + wsum[2][tid] + wsum[3][tid];
}

// ---------------------------------------------------------------- final: mean + folded (512x16) projection

__global__ __launch_bounds__(256) void final_pool(const float* __restrict__ gsum,
                                                  const int* __restrict__ gcnt,
                                                  const float* __restrict__ wcomb,
                                                  const float* __restrict__ bcomb,
                                                  float* __restrict__ out) {
    int g = blockIdx.x;
    int tid = threadIdx.x;
    __shared__ float p[D_H];
    __shared__ float part[16][17];
    int c = gcnt[g]; if (c < 1) c = 1;
    float inv = 1.0f / (float)c;
#pragma unroll
    for (int h = 0; h < 2; ++h) {
        int i = tid + h * 256;
        float v = 0.f;
#pragma unroll
        for (int ms = 0; ms < MSPLIT; ++ms)
            v += gsum[((size_t)ms * N_GRAPHS + g) * D_H + i];
        p[i] = v * inv;
    }
    __syncthreads();
    int o = tid & 15, ch = tid >> 4;
    int k0 = ch * 32;
    float s = 0.f;
    for (int k = k0; k < k0 + 32; ++k)
        s += p[k] * wcomb[k * D_OUT + o];
    part[ch][o] = s;
    __syncthreads();
    if (tid < D_OUT) {
        float t = bcomb[tid];
        for (int ch2 = 0; ch2 < 16; ++ch2) t += part[ch2][tid];
        out[g * D_OUT + tid] = t;
    }
}

// ---------------------------------------------------------------- launch

extern "C" void kernel_launch(void* const* d_in, const int* in_sizes, int n_in,
                              void* d_out, int out_size, void* d_ws, size_t ws_size,
                              hipStream_t stream) {
    const float* x     = (const float*)d_in[0];
    const int*   eidx  = (const int*)d_in[1];   // [2, E]
    const int*   batch = (const int*)d_in[2];
    const float* w1    = (const float*)d_in[3];
    const float* b1    = (const float*)d_in[4];
    const float* w2    = (const float*)d_in[5];
    const float* b2    = (const float*)d_in[6];
    const float* wc    = (const float*)d_in[7];
    const float* bc    = (const float*)d_in[8];
    float* out = (float*)d_out;
    const int* row = eidx;
    const int* col = eidx + N_EDGES;

    char* p = (char*)d_ws;
    auto alloc = [&](size_t bytes) { char* q = p; p += (bytes + 255) & ~(size_t)255; return q; };
    // zero-init region: only bucket_cnt
    char* zbase = p;
    int*   bucket_cnt = (int*)alloc((size_t)NBUK * 4);
    size_t zbytes = (size_t)(p - zbase);
    float* gsum    = (float*)alloc((size_t)MSPLIT * N_GRAPHS * D_H * 4);
    int*   rowptr  = (int*)alloc((size_t)(N_NODES + 1) * 4);
    int*   rowmid  = (int*)alloc((size_t)N_NODES * 4);
    int*   gcnt    = (int*)alloc((size_t)N_GRAPHS * 4);
    int*   gstart  = (int*)alloc((size_t)(N_GRAPHS + 1) * 4);
    float* invdeg  = (float*)alloc((size_t)N_NODES * 4);
    float* wcomb   = (float*)alloc((size_t)D_H * D_OUT * 4);
    float* bcomb   = (float*)alloc((size_t)D_OUT * 4);
    unsigned* edge_buf = (unsigned*)alloc((size_t)NBUK * BUK_CAP * 4);
    unsigned short* csr_col = (unsigned short*)alloc((size_t)N_EDGES * 2);
    unsigned short* xf  = (unsigned short*)alloc((size_t)(N_NODES + 1) * 64 * 2);  // fp8x2 + zero row
    unsigned short* h0f = (unsigned short*)alloc((size_t)(N_NODES + 1) * 64 * 2);  // fp8x2 + zero row
    unsigned short* h1f = (unsigned short*)alloc((size_t)(N_NODES + 1) * 64 * 2);  // fp8x2 + zero row
    unsigned* h3b  = (unsigned*)alloc((size_t)N_NODES * 64 * 4);                   // bf16x2 node-major
    unsigned short* w1p = (unsigned short*)alloc((size_t)D_IN * D_H * 2);
    float* accf    = (float*)alloc((size_t)N_NODES * 128 * 4);                     // f32 phase-0 partials

    (void)hipMemsetAsync(zbase, 0, zbytes, stream);

    prep<<<12790, 256, 0, stream>>>(x, xf, w1, w1p, w2, wc, b2, bc, batch,
                                    wcomb, bcomb, gcnt, gstart, h0f, h1f);

    partition_edges<<<P1_BLOCKS, 512, 0, stream>>>(row, col, bucket_cnt, edge_buf);
    finalize_csr<<<NBUK, 512, 0, stream>>>(edge_buf, bucket_cnt, rowptr, rowmid,
                                           invdeg, csr_col);

    int pgrid = (N_NODES + 31) / 32;   // 8 rows/wave, 4 waves/block
    // hop 1
    propagate_half<<<pgrid, 256, 0, stream>>>(xf, accf, h0f, nullptr, 0, 0, 8.0f,
                                              rowptr, rowmid, csr_col, invdeg);
    propagate_half<<<pgrid, 256, 0, stream>>>(xf, accf, h0f, nullptr, 1, 0, 8.0f,
                                              rowptr, rowmid, csr_col, invdeg);
    // hop 2
    propagate_half<<<pgrid, 256, 0, stream>>>(h0f, accf, h1f, nullptr, 0, 0, 8.0f,
                                              rowptr, rowmid, csr_col, invdeg);
    propagate_half<<<pgrid, 256, 0, stream>>>(h0f, accf, h1f, nullptr, 1, 0, 8.0f,
                                              rowptr, rowmid, csr_col, invdeg);
    // hop 3 (bf16 out for the GEMM)
    propagate_half<<<pgrid, 256, 0, stream>>>(h1f, accf, nullptr, h3b, 0, 1, 1.0f / 64.0f,
                                              rowptr, rowmid, csr_col, invdeg);
    propagate_half<<<pgrid, 256, 0, stream>>>(h1f, accf, nullptr, h3b, 1, 1, 1.0f / 64.0f,
                                              rowptr, rowmid, csr_col, invdeg);

    dim3 ggrid(N_GRAPHS, D_H / 128, MSPLIT);
    gemm_graph_pool<<<ggrid, 256, 0, stream>>>((const unsigned short*)h3b, w1p, b1,
                                               gstart, gsum);
    final_pool<<<N_GRAPHS, 256, 0, stream>>>(gsum, gcnt, wcomb, bcomb, out);
}

// Round 4
// 254.273 us; speedup vs baseline: 1.1771x; 1.1771x over previous
//
#include <hip/hip_runtime.h>
#include <hip/hip_bf16.h>
#include <hip/hip_fp8.h>

#define N_NODES 50000
#define N_EDGES 1600000
#define N_GRAPHS 64
#define D_IN 128
#define D_H 512
#define D_OUT 16

// atomic-free CSR build: buckets of 128 rows, 391 blocks for both phases
#define NBUK 391                      // ceil(50000/128)
#define BUK_CAP 4608                  // mean 4092 + ~8 sigma
#define P1_EDGES 4096                 // edges per partition block
#define P1_BLOCKS ((N_EDGES + P1_EDGES - 1) / P1_EDGES)   // 391

#define MSPLIT 8                      // M-tile interleave factor for the GEMM

// 3-way column tiling: each tile's source slice = 16667 rows x 128B = 2.13MB,
// fits a 4MB per-XCD L2 with room for csr_col/output streams.
#define TB0 16667
#define TB1 33334

typedef short bf16x8 __attribute__((ext_vector_type(8)));
typedef float f32x4 __attribute__((ext_vector_type(4)));

static __device__ __forceinline__ unsigned short f2bf(float f) {
    __hip_bfloat16 h = __float2bfloat16(f);   // RNE
    return *(unsigned short*)&h;
}

static __device__ __forceinline__ float2 fp8x2_dec(unsigned short u) {
    __hip_fp8x2_e4m3 p;
    p.__x = (__hip_fp8x2_storage_t)u;
    return static_cast<float2>(p);
}

static __device__ __forceinline__ unsigned short fp8x2_enc(float a, float b) {
    __hip_fp8_e4m3 pa(a), pb(b);
    return (unsigned short)((unsigned)pa.__x | ((unsigned)pb.__x << 8));
}

// decode 16 fp8 (one uint4 = 16B slice) and accumulate into acc[16]
static __device__ __forceinline__ void dec16_add(uint4 u, float* acc) {
    unsigned vv[4] = {u.x, u.y, u.z, u.w};
#pragma unroll
    for (int w = 0; w < 4; ++w) {
        float2 a = fp8x2_dec((unsigned short)(vv[w] & 0xFFFFu));
        float2 b = fp8x2_dec((unsigned short)(vv[w] >> 16));
        acc[w * 4 + 0] += a.x; acc[w * 4 + 1] += a.y;
        acc[w * 4 + 2] += b.x; acc[w * 4 + 3] += b.y;
    }
}

// ---------------------------------------------------------------- CSR build (atomic-free)
// P1: 391 blocks x 512 threads, 4096 edges each. rec = (buk:9)<<23 | (rlow:7)<<16 | col:16.

__global__ __launch_bounds__(512) void partition_edges(const int* __restrict__ row,
                                                       const int* __restrict__ col,
                                                       int* __restrict__ bucket_cnt,
                                                       unsigned* __restrict__ edge_buf) {
    __shared__ unsigned recs[P1_EDGES];     // 16 KB
    __shared__ unsigned sorted[P1_EDGES];   // 16 KB
    __shared__ int hist4[4][NBUK];          // per-wave-pair counts -> local bases
    __shared__ int cur4[4][NBUK];
    __shared__ int gbase[NBUK];
    __shared__ int scan[512];
    int tid = threadIdx.x;
    int w2 = tid >> 7;                      // wave-pair 0..3
    int e0 = blockIdx.x * P1_EDGES;
    int m = N_EDGES - e0; if (m > P1_EDGES) m = P1_EDGES;

    for (int i = tid; i < 4 * NBUK; i += 512) ((int*)hist4)[i] = 0;
    for (int i = tid; i < 4 * NBUK; i += 512) ((int*)cur4)[i] = 0;
    __syncthreads();
    for (int i = tid; i < m; i += 512) {
        int r = row[e0 + i];
        int c = col[e0 + i];
        int buk = r >> 7;
        recs[i] = ((unsigned)buk << 23) | ((unsigned)(r & 127) << 16) | (unsigned)c;
        atomicAdd(&hist4[w2][buk], 1);
    }
    __syncthreads();
    int tot = 0;
    if (tid < NBUK) tot = hist4[0][tid] + hist4[1][tid] + hist4[2][tid] + hist4[3][tid];
    scan[tid] = (tid < NBUK) ? tot : 0;
    __syncthreads();
    for (int off = 1; off < 512; off <<= 1) {
        int v = (tid >= off) ? scan[tid - off] : 0;
        __syncthreads();
        scan[tid] += v;
        __syncthreads();
    }
    if (tid < NBUK) {
        int run = (tid == 0) ? 0 : scan[tid - 1];   // block-local excl base
        gbase[tid] = (tot > 0) ? atomicAdd(&bucket_cnt[tid], tot) : 0;  // reserve range
#pragma unroll
        for (int w = 0; w < 4; ++w) {               // per-sub-group local bases
            int c = hist4[w][tid];
            hist4[w][tid] = run;
            run += c;
        }
    }
    __syncthreads();
    for (int i = tid; i < m; i += 512) {            // rank + reorder (bucket-major)
        unsigned rec = recs[i];
        int buk = rec >> 23;
        int rank = atomicAdd(&cur4[w2][buk], 1);
        sorted[hist4[w2][buk] + rank] = rec;
    }
    __syncthreads();
    for (int p = tid; p < m; p += 512) {            // coalesced-run writes
        unsigned rec = sorted[p];
        int buk = rec >> 23;
        edge_buf[(size_t)buk * BUK_CAP + gbase[buk] + (p - hist4[0][buk])] = rec;
    }
}

// P2: one block per bucket (391 x 512); inline scan of bucket_cnt; LDS-cursor scatter.
// Splits each row's edge list into 3 column-range segments and emits rowtile[2*r+{0,1}].
__global__ __launch_bounds__(512) void finalize_csr(const unsigned* __restrict__ edge_buf,
                                                    const int* __restrict__ bucket_cnt,
                                                    int* __restrict__ rowptr,
                                                    int* __restrict__ rowtile,
                                                    float* __restrict__ invdeg,
                                                    unsigned short* __restrict__ csr_col) {
    __shared__ int hcnt[3][128], excl[128], cur[3][128];
    __shared__ int scan[512];
    int b = blockIdx.x;
    int tid = threadIdx.x;
    scan[tid] = (tid < NBUK) ? bucket_cnt[tid] : 0;
    __syncthreads();
    for (int off = 1; off < 512; off <<= 1) {
        int v = (tid >= off) ? scan[tid - off] : 0;
        __syncthreads();
        scan[tid] += v;
        __syncthreads();
    }
    int cnt = bucket_cnt[b];
    int base = (b == 0) ? 0 : scan[b - 1];
    const unsigned* src = edge_buf + (size_t)b * BUK_CAP;
    __syncthreads();
    if (tid < 128) {
        hcnt[0][tid] = 0; hcnt[1][tid] = 0; hcnt[2][tid] = 0;
        cur[0][tid] = 0;  cur[1][tid] = 0;  cur[2][tid] = 0;
    }
    __syncthreads();
    for (int i = tid; i < cnt; i += 512) {
        unsigned rec = src[i];
        int rl = (rec >> 16) & 127;
        unsigned c = rec & 0xFFFFu;
        int t = (c >= TB1) ? 2 : (c >= TB0 ? 1 : 0);
        atomicAdd(&hcnt[t][rl], 1);
    }
    __syncthreads();
    int tot_r = (tid < 128) ? (hcnt[0][tid] + hcnt[1][tid] + hcnt[2][tid]) : 0;
    scan[tid] = tot_r;
    __syncthreads();
    for (int off = 1; off < 512; off <<= 1) {
        int v = (tid >= off) ? scan[tid - off] : 0;
        __syncthreads();
        scan[tid] += v;
        __syncthreads();
    }
    if (tid < 128) excl[tid] = (tid == 0) ? 0 : scan[tid - 1];
    __syncthreads();
    int r = b * 128 + tid;
    if (tid < 128 && r < N_NODES) {
        int rb = base + excl[tid];
        rowptr[r] = rb;
        rowtile[2 * r + 0] = rb + hcnt[0][tid];
        rowtile[2 * r + 1] = rb + hcnt[0][tid] + hcnt[1][tid];
        invdeg[r] = 1.0f / (float)(tot_r + 1);   // +1: self loop
    }
    if (b == NBUK - 1 && tid == 0) rowptr[N_NODES] = base + cnt;
    for (int i = tid; i < cnt; i += 512) {
        unsigned rec = src[i];
        int rl = (rec >> 16) & 127;
        unsigned c = rec & 0xFFFFu;
        int t = (c >= TB1) ? 2 : (c >= TB0 ? 1 : 0);
        int off = (t == 0) ? 0 : (t == 1 ? hcnt[0][rl] : hcnt[0][rl] + hcnt[1][rl]);
        int pos = excl[rl] + off + atomicAdd(&cur[t][rl], 1);
        csr_col[base + pos] = (unsigned short)c;
    }
}

// ---------------------------------------------------------------- merged prep
// [0,12500): convert_x; [12500,12756): make_w1p; [12756,12790): fold_w + graph bounds
// + zero-row sentinels for the gather (row N_NODES of xf/h0f/h1f).

__global__ __launch_bounds__(256) void prep(const float* __restrict__ x,
                                            unsigned short* __restrict__ xf,
                                            const float* __restrict__ w1,
                                            unsigned short* __restrict__ w1p,
                                            const float* __restrict__ w2,
                                            const float* __restrict__ wc,
                                            const float* __restrict__ b2,
                                            const float* __restrict__ bc,
                                            const int* __restrict__ batch,
                                            float* __restrict__ wcomb,
                                            float* __restrict__ bcomb,
                                            int* __restrict__ gcnt,
                                            int* __restrict__ gstart,
                                            unsigned short* __restrict__ h0f,
                                            unsigned short* __restrict__ h1f) {
    int b = blockIdx.x;
    int tid = threadIdx.x;
    if (b < 12500) {                                // convert_x: 12500*256 == N*64 exactly
        int i = b * 256 + tid;
        float2 v = ((const float2*)x)[i];
        xf[i] = fp8x2_enc(v.x, v.y);
        return;
    }
    if (b < 12756) {                                // make_w1p: 256 blocks, 65536 elems
        int i = (b - 12500) * 256 + tid;
        int j = i & 7, lane = (i >> 3) & 63, s = (i >> 9) & 3, t = i >> 11;
        int k = s * 32 + (lane >> 4) * 8 + j;
        int n = t * 16 + (lane & 15);
        w1p[i] = f2bf(w1[(size_t)k * D_H + n]);
        return;
    }
    int fb = b - 12756;                             // fold_w blocks 0..33
    if (fb == 33) {
        if (tid < N_GRAPHS) {
            int g = tid;
            int lo = 0, hi = N_NODES;
            while (lo < hi) { int mid = (lo + hi) >> 1; if (batch[mid] < g) lo = mid + 1; else hi = mid; }
            int a = lo;
            lo = 0; hi = N_NODES;
            while (lo < hi) { int mid = (lo + hi) >> 1; if (batch[mid] < g + 1) lo = mid + 1; else hi = mid; }
            gcnt[g] = lo - a;
            gstart[g] = a;
            if (g == N_GRAPHS - 1) gstart[N_GRAPHS] = N_NODES;
        } else if (tid >= 64 && tid < 256) {        // zero-row sentinels (3 bufs x 64 u16)
            int t = tid - 64;
            unsigned short* bp = (t < 64) ? xf : (t < 128 ? h0f : h1f);
            bp[(size_t)N_NODES * 64 + (t & 63)] = 0;
        }
        return;
    }
    int o = tid & 15, kl = tid >> 4;
    int k = fb * 16 + kl;
    if (k > D_H) return;
    const float* wr = (k < D_H) ? (w2 + (size_t)k * D_H) : b2;
    float s = 0.f;
    for (int j = 0; j < D_H; j += 4) {
        s += wr[j + 0] * wc[(j + 0) * D_OUT + o]
           + wr[j + 1] * wc[(j + 1) * D_OUT + o]
           + wr[j + 2] * wc[(j + 2) * D_OUT + o]
           + wr[j + 3] * wc[(j + 3) * D_OUT + o];
    }
    if (k < D_H) wcomb[k * D_OUT + o] = s;
    else         bcomb[o] = s + bc[o];
}

// ---------------------------------------------------------------- propagation (fp8 storage, f32 accumulate)
// IN-REGISTER COLUMN TILING: each row's edge list is pre-bucketed into 3
// column ranges ([0,16667),[16667,33334),[33334,50000)). The kernel walks the
// 3 segments sequentially with the f32 accumulators held in registers the
// whole time (no partial-sum round trip, no extra launches). Within a tile,
// gathers touch only a 2.13MB source slice -> per-XCD-L2-resident; the only
// competing streams are csr_col (3.2MB/hop, sequential) and the output write.
// Shape: 8 rows/wave, 16B/lane (1KB per gather instr); zero-row sentinel at
// N_NODES absorbs degree divergence.

__global__ __launch_bounds__(256) void propagate_fp8(const unsigned short* __restrict__ xin,
                                                     unsigned short* __restrict__ out8,
                                                     unsigned* __restrict__ out16,
                                                     int last, float extra,
                                                     const int* __restrict__ rowptr,
                                                     const int* __restrict__ rowtile,
                                                     const unsigned short* __restrict__ csr_col,
                                                     const float* __restrict__ invdeg) {
    int lane = threadIdx.x & 63;
    int wave = threadIdx.x >> 6;
    int l8   = lane & 7;                 // 16B slice within the row (features 16*l8..16*l8+15)
    int grp  = lane >> 3;                // row-in-wave 0..7
    int r = blockIdx.x * 32 + wave * 8 + grp;
    bool rv = (r < N_NODES);
    int rc = rv ? r : 0;
    int pbeg = rowptr[rc];
    int pend = rowptr[rc + 1];
    int t0e  = rowtile[2 * rc + 0];
    int t1e  = rowtile[2 * rc + 1];

    float acc[16];
#pragma unroll
    for (int i = 0; i < 16; ++i) acc[i] = 0.f;
    {   // self loop (sequential coalesced read of own row)
        uint4 u = *(const uint4*)(xin + (size_t)rc * 64 + l8 * 8);
        dec16_add(u, acc);
    }

    int base = lane & 56;
    for (int t = 0; t < 3; ++t) {
        int beg = (t == 0) ? pbeg : (t == 1 ? t0e : t1e);
        int end = (t == 0) ? t0e  : (t == 1 ? t1e : pend);
        int nn = rv ? (end - beg) : 0;

        // wave-max segment length (idle groups/slots read the zero row)
        int nmax = nn;
        { int v = __shfl_xor(nmax, 8, 64);  nmax = v > nmax ? v : nmax; }
        { int v = __shfl_xor(nmax, 16, 64); nmax = v > nmax ? v : nmax; }
        { int v = __shfl_xor(nmax, 32, 64); nmax = v > nmax ? v : nmax; }
        if (nmax == 0) continue;          // wave-uniform

        // first batch of 8 column indices: lane l8 holds col (myrow, jb + l8)
        int cv;
        {
            int jj = l8;
            int idx = (jj < nn) ? beg + jj : 0;
            unsigned short cl = csr_col[idx];
            cv = (jj < nn) ? (int)cl : N_NODES;
        }
        for (int jb = 0; jb < nmax; jb += 8) {
            uint4 u[8];
#pragma unroll
            for (int q = 0; q < 8; ++q) {
                int c = __shfl(cv, base + q, 64);
                u[q] = *(const uint4*)(xin + (size_t)c * 64 + l8 * 8);
            }
            // prefetch next batch's column indices while gathers are in flight
            int jn = jb + 8 + l8;
            int idxn = (jn < nn) ? beg + jn : 0;
            unsigned short cln = csr_col[idxn];
            int cvn = (jn < nn) ? (int)cln : N_NODES;
#pragma unroll
            for (int q = 0; q < 8; ++q) dec16_add(u[q], acc);
            cv = cvn;
        }
    }

    if (!rv) return;

    float s = invdeg[r] * extra;
#pragma unroll
    for (int i = 0; i < 16; ++i) acc[i] *= s;

    if (last) {
        uint4 w0, w1v;
        w0.x = (unsigned)f2bf(acc[0])  | ((unsigned)f2bf(acc[1])  << 16);
        w0.y = (unsigned)f2bf(acc[2])  | ((unsigned)f2bf(acc[3])  << 16);
        w0.z = (unsigned)f2bf(acc[4])  | ((unsigned)f2bf(acc[5])  << 16);
        w0.w = (unsigned)f2bf(acc[6])  | ((unsigned)f2bf(acc[7])  << 16);
        w1v.x = (unsigned)f2bf(acc[8])  | ((unsigned)f2bf(acc[9])  << 16);
        w1v.y = (unsigned)f2bf(acc[10]) | ((unsigned)f2bf(acc[11]) << 16);
        w1v.z = (unsigned)f2bf(acc[12]) | ((unsigned)f2bf(acc[13]) << 16);
        w1v.w = (unsigned)f2bf(acc[14]) | ((unsigned)f2bf(acc[15]) << 16);
        unsigned* dst = out16 + (size_t)r * 64 + l8 * 8;
        *(uint4*)dst = w0;
        *(uint4*)(dst + 4) = w1v;
    } else {
        uint4 w;
        w.x = (unsigned)fp8x2_enc(acc[0],  acc[1])  | ((unsigned)fp8x2_enc(acc[2],  acc[3])  << 16);
        w.y = (unsigned)fp8x2_enc(acc[4],  acc[5])  | ((unsigned)fp8x2_enc(acc[6],  acc[7])  << 16);
        w.z = (unsigned)fp8x2_enc(acc[8],  acc[9])  | ((unsigned)fp8x2_enc(acc[10], acc[11]) << 16);
        w.w = (unsigned)fp8x2_enc(acc[12], acc[13]) | ((unsigned)fp8x2_enc(acc[14], acc[15]) << 16);
        *(uint4*)(out8 + (size_t)r * 64 + l8 * 8) = w;
    }
}

// ---------------------------------------------------------------- MFMA GEMM + pool, register-only epilogue
// grid (64 graphs, 4 col-groups, MSPLIT) = 2048 blocks (8/CU). Pool sum computed
// straight from the MFMA C-layout: lane (col=l15, quad) holds rows quad*4+rg of the
// wave's 16-row strip -> per-lane reg sum + shfl_xor(16,32). No per-tile barriers,
// no 34KB LDS tile (only 2KB cross-wave buffer). Zero atomics.

__global__ __launch_bounds__(256) void gemm_graph_pool(const unsigned short* __restrict__ h3b,
                                                       const unsigned short* __restrict__ w1p,
                                                       const float* __restrict__ b1,
                                                       const int* __restrict__ gstart,
                                                       float* __restrict__ gsum) {
    __shared__ float wsum[4][128];
    int tid = threadIdx.x;
    int lane = tid & 63, wave = tid >> 6;
    int quad = lane >> 4, l15 = lane & 15;
    int g = blockIdx.x;
    int nbase = blockIdx.y * 128;
    int ms = blockIdx.z;
    int r0 = gstart[g], r1 = gstart[g + 1];

    float b1v[8];
#pragma unroll
    for (int t = 0; t < 8; ++t) b1v[t] = b1[nbase + t * 16 + l15];

    const unsigned short* bbase = w1p + ((size_t)(blockIdx.y * 8) * 4 * 64 + lane) * 8;

    float gaccT[8];
#pragma unroll
    for (int t = 0; t < 8; ++t) gaccT[t] = 0.f;

    for (int mbase = r0 + ms * 64; mbase < r1; mbase += 64 * MSPLIT) {
        int m = mbase + wave * 16 + l15;
        int mc = m < N_NODES ? m : N_NODES - 1;      // clamp; invalid rows masked below
        const unsigned short* arow = h3b + (size_t)mc * 128 + quad * 8;
        bf16x8 afrag[4];
#pragma unroll
        for (int s = 0; s < 4; ++s)
            afrag[s] = *(const bf16x8*)(arow + s * 32);

        int rowbase = mbase + wave * 16 + quad * 4;  // this lane's C rows: rowbase+rg
#pragma unroll
        for (int t = 0; t < 8; ++t) {
            f32x4 acc = (f32x4){0.f, 0.f, 0.f, 0.f};
#pragma unroll
            for (int s = 0; s < 4; ++s) {
                bf16x8 bfrag = *(const bf16x8*)(bbase + (size_t)(t * 4 + s) * 64 * 8);
                acc = __builtin_amdgcn_mfma_f32_16x16x32_bf16(afrag[s], bfrag, acc, 0, 0, 0);
            }
#pragma unroll
            for (int rg = 0; rg < 4; ++rg) {
                float v = acc[rg] + b1v[t];
                v = v > 0.f ? v : 0.f;
                gaccT[t] += (rowbase + rg < r1) ? v : 0.f;
            }
        }
    }
    // sum the 4 quads (rows 0..15 of the wave strip) per column
#pragma unroll
    for (int t = 0; t < 8; ++t) {
        gaccT[t] += __shfl_xor(gaccT[t], 16, 64);
        gaccT[t] += __shfl_xor(gaccT[t], 32, 64);
    }
    if (quad == 0) {
#pragma unroll
        for (int t = 0; t < 8; ++t)
            wsum[wave][t * 16 + l15] = gaccT[t];
    }
    __syncthreads();
    if (tid < 128)
        gsum[((size_t)ms * N_GRAPHS + g) * D_H + nbase + tid] =
            wsum[0][tid] + wsum[1][tid] + wsum[2][tid] + wsum[3][tid];
}

// ---------------------------------------------------------------- final: mean + folded (512x16) projection

__global__ __launch_bounds__(256) void final_pool(const float* __restrict__ gsum,
                                                  const int* __restrict__ gcnt,
                                                  const float* __restrict__ wcomb,
                                                  const float* __restrict__ bcomb,
                                                  float* __restrict__ out) {
    int g = blockIdx.x;
    int tid = threadIdx.x;
    __shared__ float p[D_H];
    __shared__ float part[16][17];
    int c = gcnt[g]; if (c < 1) c = 1;
    float inv = 1.0f / (float)c;
#pragma unroll
    for (int h = 0; h < 2; ++h) {
        int i = tid + h * 256;
        float v = 0.f;
#pragma unroll
        for (int ms = 0; ms < MSPLIT; ++ms)
            v += gsum[((size_t)ms * N_GRAPHS + g) * D_H + i];
        p[i] = v * inv;
    }
    __syncthreads();
    int o = tid & 15, ch = tid >> 4;
    int k0 = ch * 32;
    float s = 0.f;
    for (int k = k0; k < k0 + 32; ++k)
        s += p[k] * wcomb[k * D_OUT + o];
    part[ch][o] = s;
    __syncthreads();
    if (tid < D_OUT) {
        float t = bcomb[tid];
        for (int ch2 = 0; ch2 < 16; ++ch2) t += part[ch2][tid];
        out[g * D_OUT + tid] = t;
    }
}

// ---------------------------------------------------------------- launch

extern "C" void kernel_launch(void* const* d_in, const int* in_sizes, int n_in,
                              void* d_out, int out_size, void* d_ws, size_t ws_size,
                              hipStream_t stream) {
    const float* x     = (const float*)d_in[0];
    const int*   eidx  = (const int*)d_in[1];   // [2, E]
    const int*   batch = (const int*)d_in[2];
    const float* w1    = (const float*)d_in[3];
    const float* b1    = (const float*)d_in[4];
    const float* w2    = (const float*)d_in[5];
    const float* b2    = (const float*)d_in[6];
    const float* wc    = (const float*)d_in[7];
    const float* bc    = (const float*)d_in[8];
    float* out = (float*)d_out;
    const int* row = eidx;
    const int* col = eidx + N_EDGES;

    char* p = (char*)d_ws;
    auto alloc = [&](size_t bytes) { char* q = p; p += (bytes + 255) & ~(size_t)255; return q; };
    // zero-init region: only bucket_cnt
    char* zbase = p;
    int*   bucket_cnt = (int*)alloc((size_t)NBUK * 4);
    size_t zbytes = (size_t)(p - zbase);
    float* gsum    = (float*)alloc((size_t)MSPLIT * N_GRAPHS * D_H * 4);
    int*   rowptr  = (int*)alloc((size_t)(N_NODES + 1) * 4);
    int*   rowtile = (int*)alloc((size_t)N_NODES * 2 * 4);
    int*   gcnt    = (int*)alloc((size_t)N_GRAPHS * 4);
    int*   gstart  = (int*)alloc((size_t)(N_GRAPHS + 1) * 4);
    float* invdeg  = (float*)alloc((size_t)N_NODES * 4);
    float* wcomb   = (float*)alloc((size_t)D_H * D_OUT * 4);
    float* bcomb   = (float*)alloc((size_t)D_OUT * 4);
    unsigned* edge_buf = (unsigned*)alloc((size_t)NBUK * BUK_CAP * 4);
    unsigned short* csr_col = (unsigned short*)alloc((size_t)N_EDGES * 2);
    unsigned short* xf  = (unsigned short*)alloc((size_t)(N_NODES + 1) * 64 * 2);  // fp8x2 + zero row
    unsigned short* h0f = (unsigned short*)alloc((size_t)(N_NODES + 1) * 64 * 2);  // fp8x2 + zero row
    unsigned short* h1f = (unsigned short*)alloc((size_t)(N_NODES + 1) * 64 * 2);  // fp8x2 + zero row
    unsigned* h3b  = (unsigned*)alloc((size_t)N_NODES * 64 * 4);                   // bf16x2 node-major
    unsigned short* w1p = (unsigned short*)alloc((size_t)D_IN * D_H * 2);

    (void)hipMemsetAsync(zbase, 0, zbytes, stream);

    prep<<<12790, 256, 0, stream>>>(x, xf, w1, w1p, w2, wc, b2, bc, batch,
                                    wcomb, bcomb, gcnt, gstart, h0f, h1f);

    partition_edges<<<P1_BLOCKS, 512, 0, stream>>>(row, col, bucket_cnt, edge_buf);
    finalize_csr<<<NBUK, 512, 0, stream>>>(edge_buf, bucket_cnt, rowptr, rowtile,
                                           invdeg, csr_col);

    int pgrid = (N_NODES + 31) / 32;   // 8 rows/wave, 4 waves/block
    propagate_fp8<<<pgrid, 256, 0, stream>>>(xf,  h0f, nullptr, 0, 8.0f,
                                             rowptr, rowtile, csr_col, invdeg);
    propagate_fp8<<<pgrid, 256, 0, stream>>>(h0f, h1f, nullptr, 0, 8.0f,
                                             rowptr, rowtile, csr_col, invdeg);
    propagate_fp8<<<pgrid, 256, 0, stream>>>(h1f, nullptr, h3b, 1, 1.0f / 64.0f,
                                             rowptr, rowtile, csr_col, invdeg);

    dim3 ggrid(N_GRAPHS, D_H / 128, MSPLIT);
    gemm_graph_pool<<<ggrid, 256, 0, stream>>>((const unsigned short*)h3b, w1p, b1,
                                               gstart, gsum);
    final_pool<<<N_GRAPHS, 256, 0, stream>>>(gsum, gcnt, wcomb, bcomb, out);
}

// Round 5
// 235.419 us; speedup vs baseline: 1.2713x; 1.0801x over previous
//
#include <hip/hip_runtime.h>
#include <hip/hip_bf16.h>
#include <hip/hip_fp8.h>

#define N_NODES 50000
#define N_EDGES 1600000
#define N_GRAPHS 64
#define D_IN 128
#define D_H 512
#define D_OUT 16

// atomic-free CSR build: buckets of 128 rows, 391 blocks for both phases
#define NBUK 391                      // ceil(50000/128)
#define BUK_CAP 4608                  // mean 4092 + ~8 sigma
#define P1_EDGES 4096                 // edges per partition block
#define P1_BLOCKS ((N_EDGES + P1_EDGES - 1) / P1_EDGES)   // 391

#define MSPLIT 8                      // M-tile interleave factor for the GEMM

typedef short bf16x8 __attribute__((ext_vector_type(8)));
typedef float f32x4 __attribute__((ext_vector_type(4)));
typedef float f32x2 __attribute__((ext_vector_type(2)));

static __device__ __forceinline__ unsigned short f2bf(float f) {
    __hip_bfloat16 h = __float2bfloat16(f);   // RNE
    return *(unsigned short*)&h;
}

static __device__ __forceinline__ float2 fp8x2_dec(unsigned short u) {
    __hip_fp8x2_e4m3 p;
    p.__x = (__hip_fp8x2_storage_t)u;
    return static_cast<float2>(p);
}

static __device__ __forceinline__ unsigned short fp8x2_enc(float a, float b) {
    __hip_fp8_e4m3 pa(a), pb(b);
    return (unsigned short)((unsigned)pa.__x | ((unsigned)pb.__x << 8));
}

// decode 16 fp8 (one uint4 = 16B slice) and accumulate into 8 packed f32x2
// (acc[w*2+0] = feats 4w+0,4w+1; acc[w*2+1] = feats 4w+2,4w+3) -> v_pk_add_f32
static __device__ __forceinline__ void dec16_add(uint4 u, f32x2* acc) {
    unsigned vv[4] = {u.x, u.y, u.z, u.w};
#pragma unroll
    for (int w = 0; w < 4; ++w) {
        float2 a = fp8x2_dec((unsigned short)(vv[w] & 0xFFFFu));
        float2 b = fp8x2_dec((unsigned short)(vv[w] >> 16));
        f32x2 av; av.x = a.x; av.y = a.y;
        f32x2 bv; bv.x = b.x; bv.y = b.y;
        acc[w * 2 + 0] += av;
        acc[w * 2 + 1] += bv;
    }
}

// ---------------------------------------------------------------- CSR build (atomic-free)
// P1: 391 blocks x 512 threads, 4096 edges each. rec = (buk:9)<<23 | (rlow:7)<<16 | col:16.

__global__ __launch_bounds__(512) void partition_edges(const int* __restrict__ row,
                                                       const int* __restrict__ col,
                                                       int* __restrict__ bucket_cnt,
                                                       unsigned* __restrict__ edge_buf) {
    __shared__ unsigned recs[P1_EDGES];     // 16 KB
    __shared__ unsigned sorted[P1_EDGES];   // 16 KB
    __shared__ int hist4[4][NBUK];          // per-wave-pair counts -> local bases
    __shared__ int cur4[4][NBUK];
    __shared__ int gbase[NBUK];
    __shared__ int scan[512];
    int tid = threadIdx.x;
    int w2 = tid >> 7;                      // wave-pair 0..3
    int e0 = blockIdx.x * P1_EDGES;
    int m = N_EDGES - e0; if (m > P1_EDGES) m = P1_EDGES;

    for (int i = tid; i < 4 * NBUK; i += 512) ((int*)hist4)[i] = 0;
    for (int i = tid; i < 4 * NBUK; i += 512) ((int*)cur4)[i] = 0;
    __syncthreads();
    for (int i = tid; i < m; i += 512) {
        int r = row[e0 + i];
        int c = col[e0 + i];
        int buk = r >> 7;
        recs[i] = ((unsigned)buk << 23) | ((unsigned)(r & 127) << 16) | (unsigned)c;
        atomicAdd(&hist4[w2][buk], 1);
    }
    __syncthreads();
    int tot = 0;
    if (tid < NBUK) tot = hist4[0][tid] + hist4[1][tid] + hist4[2][tid] + hist4[3][tid];
    scan[tid] = (tid < NBUK) ? tot : 0;
    __syncthreads();
    for (int off = 1; off < 512; off <<= 1) {
        int v = (tid >= off) ? scan[tid - off] : 0;
        __syncthreads();
        scan[tid] += v;
        __syncthreads();
    }
    if (tid < NBUK) {
        int run = (tid == 0) ? 0 : scan[tid - 1];   // block-local excl base
        gbase[tid] = (tot > 0) ? atomicAdd(&bucket_cnt[tid], tot) : 0;  // reserve range
#pragma unroll
        for (int w = 0; w < 4; ++w) {               // per-sub-group local bases
            int c = hist4[w][tid];
            hist4[w][tid] = run;
            run += c;
        }
    }
    __syncthreads();
    for (int i = tid; i < m; i += 512) {            // rank + reorder (bucket-major)
        unsigned rec = recs[i];
        int buk = rec >> 23;
        int rank = atomicAdd(&cur4[w2][buk], 1);
        sorted[hist4[w2][buk] + rank] = rec;
    }
    __syncthreads();
    for (int p = tid; p < m; p += 512) {            // coalesced-run writes
        unsigned rec = sorted[p];
        int buk = rec >> 23;
        edge_buf[(size_t)buk * BUK_CAP + gbase[buk] + (p - hist4[0][buk])] = rec;
    }
}

// P2: one block per bucket (391 x 512); inline scan of bucket_cnt; LDS-cursor scatter.
__global__ __launch_bounds__(512) void finalize_csr(const unsigned* __restrict__ edge_buf,
                                                    const int* __restrict__ bucket_cnt,
                                                    int* __restrict__ rowptr,
                                                    float* __restrict__ invdeg,
                                                    unsigned short* __restrict__ csr_col) {
    __shared__ int hist[128], excl[128], cur[128];
    __shared__ int scan[512];
    int b = blockIdx.x;
    int tid = threadIdx.x;
    scan[tid] = (tid < NBUK) ? bucket_cnt[tid] : 0;
    __syncthreads();
    for (int off = 1; off < 512; off <<= 1) {
        int v = (tid >= off) ? scan[tid - off] : 0;
        __syncthreads();
        scan[tid] += v;
        __syncthreads();
    }
    int cnt = bucket_cnt[b];
    int base = (b == 0) ? 0 : scan[b - 1];
    const unsigned* src = edge_buf + (size_t)b * BUK_CAP;
    __syncthreads();
    if (tid < 128) { hist[tid] = 0; cur[tid] = 0; }
    __syncthreads();
    for (int i = tid; i < cnt; i += 512)
        atomicAdd(&hist[(src[i] >> 16) & 127], 1);
    __syncthreads();
    scan[tid] = (tid < 128) ? hist[tid] : 0;
    __syncthreads();
    for (int off = 1; off < 512; off <<= 1) {
        int v = (tid >= off) ? scan[tid - off] : 0;
        __syncthreads();
        scan[tid] += v;
        __syncthreads();
    }
    if (tid < 128) excl[tid] = (tid == 0) ? 0 : scan[tid - 1];
    __syncthreads();
    int r = b * 128 + tid;
    if (tid < 128 && r < N_NODES) {
        rowptr[r] = base + excl[tid];
        invdeg[r] = 1.0f / (float)(hist[tid] + 1);   // +1: self loop
    }
    if (b == NBUK - 1 && tid == 0) rowptr[N_NODES] = base + cnt;
    for (int i = tid; i < cnt; i += 512) {
        unsigned rec = src[i];
        int rl = (rec >> 16) & 127;
        int pos = excl[rl] + atomicAdd(&cur[rl], 1);
        csr_col[base + pos] = (unsigned short)(rec & 0xFFFFu);
    }
}

// ---------------------------------------------------------------- merged prep
// [0,12500): convert_x; [12500,12756): make_w1p; [12756,12790): fold_w + graph bounds
// + zero-row sentinels for the gather (row N_NODES of xf/h0f/h1f).

__global__ __launch_bounds__(256) void prep(const float* __restrict__ x,
                                            unsigned short* __restrict__ xf,
                                            const float* __restrict__ w1,
                                            unsigned short* __restrict__ w1p,
                                            const float* __restrict__ w2,
                                            const float* __restrict__ wc,
                                            const float* __restrict__ b2,
                                            const float* __restrict__ bc,
                                            const int* __restrict__ batch,
                                            float* __restrict__ wcomb,
                                            float* __restrict__ bcomb,
                                            int* __restrict__ gcnt,
                                            int* __restrict__ gstart,
                                            unsigned short* __restrict__ h0f,
                                            unsigned short* __restrict__ h1f) {
    int b = blockIdx.x;
    int tid = threadIdx.x;
    if (b < 12500) {                                // convert_x: 12500*256 == N*64 exactly
        int i = b * 256 + tid;
        float2 v = ((const float2*)x)[i];
        xf[i] = fp8x2_enc(v.x, v.y);
        return;
    }
    if (b < 12756) {                                // make_w1p: 256 blocks, 65536 elems
        int i = (b - 12500) * 256 + tid;
        int j = i & 7, lane = (i >> 3) & 63, s = (i >> 9) & 3, t = i >> 11;
        int k = s * 32 + (lane >> 4) * 8 + j;
        int n = t * 16 + (lane & 15);
        w1p[i] = f2bf(w1[(size_t)k * D_H + n]);
        return;
    }
    int fb = b - 12756;                             // fold_w blocks 0..33
    if (fb == 33) {
        if (tid < N_GRAPHS) {
            int g = tid;
            int lo = 0, hi = N_NODES;
            while (lo < hi) { int mid = (lo + hi) >> 1; if (batch[mid] < g) lo = mid + 1; else hi = mid; }
            int a = lo;
            lo = 0; hi = N_NODES;
            while (lo < hi) { int mid = (lo + hi) >> 1; if (batch[mid] < g + 1) lo = mid + 1; else hi = mid; }
            gcnt[g] = lo - a;
            gstart[g] = a;
            if (g == N_GRAPHS - 1) gstart[N_GRAPHS] = N_NODES;
        } else if (tid >= 64 && tid < 256) {        // zero-row sentinels (3 bufs x 64 u16)
            int t = tid - 64;
            unsigned short* bp = (t < 64) ? xf : (t < 128 ? h0f : h1f);
            bp[(size_t)N_NODES * 64 + (t & 63)] = 0;
        }
        return;
    }
    int o = tid & 15, kl = tid >> 4;
    int k = fb * 16 + kl;
    if (k > D_H) return;
    const float* wr = (k < D_H) ? (w2 + (size_t)k * D_H) : b2;
    float s = 0.f;
    for (int j = 0; j < D_H; j += 4) {
        s += wr[j + 0] * wc[(j + 0) * D_OUT + o]
           + wr[j + 1] * wc[(j + 1) * D_OUT + o]
           + wr[j + 2] * wc[(j + 2) * D_OUT + o]
           + wr[j + 3] * wc[(j + 3) * D_OUT + o];
    }
    if (k < D_H) wcomb[k * D_OUT + o] = s;
    else         bcomb[o] = s + bc[o];
}

// ---------------------------------------------------------------- propagation (fp8 storage, f32 accumulate)
// Depth-2 software-pipelined gather: issue batch k+1's 8x1KB gathers BEFORE
// consuming batch k (ping-pong uA/uB, statically indexed), index stream
// prefetched two batches ahead. Per-wave outstanding lines doubles (8->16) and
// the decode of one batch (~256 SIMD-cyc) hides the next batch's L2 latency.
// Shape: 8 rows/wave, 16B/lane; zero-row sentinel at N_NODES pads everything.

__global__ __launch_bounds__(256) void propagate_fp8(const unsigned short* __restrict__ xin,
                                                     unsigned short* __restrict__ out8,
                                                     unsigned* __restrict__ out16,
                                                     int last, float extra,
                                                     const int* __restrict__ rowptr,
                                                     const unsigned short* __restrict__ csr_col,
                                                     const float* __restrict__ invdeg) {
    int lane = threadIdx.x & 63;
    int wave = threadIdx.x >> 6;
    int l8   = lane & 7;                 // 16B slice within the row (features 16*l8..16*l8+15)
    int grp  = lane >> 3;                // row-in-wave 0..7
    int r = blockIdx.x * 32 + wave * 8 + grp;
    bool rv = (r < N_NODES);
    int rc = rv ? r : 0;
    int beg = rowptr[rc], end = rowptr[rc + 1];
    int nn = rv ? (end - beg) : 0;

    // wave-max degree (idle groups/slots read the zero row)
    int nmax = nn;
    { int t = __shfl_xor(nmax, 8, 64);  if (t > nmax) nmax = t; }
    { int t = __shfl_xor(nmax, 16, 64); if (t > nmax) nmax = t; }
    { int t = __shfl_xor(nmax, 32, 64); if (t > nmax) nmax = t; }

    f32x2 acc[8];
#pragma unroll
    for (int i = 0; i < 8; ++i) acc[i] = (f32x2){0.f, 0.f};
    {   // self loop
        uint4 u = *(const uint4*)(xin + (size_t)rc * 64 + l8 * 8);
        dec16_add(u, acc);
    }

    int base = lane & 56;
    // lane l8 holds the col index for (its group's row, batch_start + l8);
    // out-of-range slots -> zero-row sentinel (always address-safe: idx 0)
    auto ldidx = [&](int jb) -> int {
        int jj = jb + l8;
        int idx = (jj < nn) ? beg + jj : 0;
        unsigned short cl = csr_col[idx];
        return (jj < nn) ? (int)cl : N_NODES;
    };

    int nb = (nmax + 7) >> 3;                 // number of 8-edge-per-group batches
    if (nb > 0) {
        uint4 uA[8], uB[8];
        {
            int cv = ldidx(0);
#pragma unroll
            for (int q = 0; q < 8; ++q) {
                int c = __shfl(cv, base + q, 64);
                uA[q] = *(const uint4*)(xin + (size_t)c * 64 + l8 * 8);
            }
        }
        int cvn = ldidx(8);                   // indices for batch 1
        int k = 0;
        while (true) {
            // invariant: uA = batch k in flight; cvn = indices for batch k+1
            if (k + 1 < nb) {
#pragma unroll
                for (int q = 0; q < 8; ++q) {
                    int c = __shfl(cvn, base + q, 64);
                    uB[q] = *(const uint4*)(xin + (size_t)c * 64 + l8 * 8);
                }
            }
            cvn = ldidx((k + 2) * 8);         // prefetch indices for k+2 (sentinel-safe)
#pragma unroll
            for (int q = 0; q < 8; ++q) dec16_add(uA[q], acc);
            ++k;
            if (k >= nb) break;
            // invariant: uB = batch k in flight; cvn = indices for batch k+1
            if (k + 1 < nb) {
#pragma unroll
                for (int q = 0; q < 8; ++q) {
                    int c = __shfl(cvn, base + q, 64);
                    uA[q] = *(const uint4*)(xin + (size_t)c * 64 + l8 * 8);
                }
            }
            cvn = ldidx((k + 2) * 8);
#pragma unroll
            for (int q = 0; q < 8; ++q) dec16_add(uB[q], acc);
            ++k;
            if (k >= nb) break;
        }
    }

    if (!rv) return;

    float s = invdeg[r] * extra;
#pragma unroll
    for (int i = 0; i < 8; ++i) acc[i] *= s;

    if (last) {
        uint4 w0, w1v;
        w0.x = (unsigned)f2bf(acc[0].x) | ((unsigned)f2bf(acc[0].y) << 16);
        w0.y = (unsigned)f2bf(acc[1].x) | ((unsigned)f2bf(acc[1].y) << 16);
        w0.z = (unsigned)f2bf(acc[2].x) | ((unsigned)f2bf(acc[2].y) << 16);
        w0.w = (unsigned)f2bf(acc[3].x) | ((unsigned)f2bf(acc[3].y) << 16);
        w1v.x = (unsigned)f2bf(acc[4].x) | ((unsigned)f2bf(acc[4].y) << 16);
        w1v.y = (unsigned)f2bf(acc[5].x) | ((unsigned)f2bf(acc[5].y) << 16);
        w1v.z = (unsigned)f2bf(acc[6].x) | ((unsigned)f2bf(acc[6].y) << 16);
        w1v.w = (unsigned)f2bf(acc[7].x) | ((unsigned)f2bf(acc[7].y) << 16);
        unsigned* dst = out16 + (size_t)r * 64 + l8 * 8;
        *(uint4*)dst = w0;
        *(uint4*)(dst + 4) = w1v;
    } else {
        uint4 w;
        w.x = (unsigned)fp8x2_enc(acc[0].x, acc[0].y) | ((unsigned)fp8x2_enc(acc[1].x, acc[1].y) << 16);
        w.y = (unsigned)fp8x2_enc(acc[2].x, acc[2].y) | ((unsigned)fp8x2_enc(acc[3].x, acc[3].y) << 16);
        w.z = (unsigned)fp8x2_enc(acc[4].x, acc[4].y) | ((unsigned)fp8x2_enc(acc[5].x, acc[5].y) << 16);
        w.w = (unsigned)fp8x2_enc(acc[6].x, acc[6].y) | ((unsigned)fp8x2_enc(acc[7].x, acc[7].y) << 16);
        *(uint4*)(out8 + (size_t)r * 64 + l8 * 8) = w;
    }
}

// ---------------------------------------------------------------- MFMA GEMM + pool, register-only epilogue
// grid (64 graphs, 4 col-groups, MSPLIT) = 2048 blocks (8/CU). Pool sum computed
// straight from the MFMA C-layout: lane (col=l15, quad) holds rows quad*4+rg of the
// wave's 16-row strip -> per-lane reg sum + shfl_xor(16,32). No per-tile barriers,
// no 34KB LDS tile (only 2KB cross-wave buffer). Zero atomics.

__global__ __launch_bounds__(256) void gemm_graph_pool(const unsigned short* __restrict__ h3b,
                                                       const unsigned short* __restrict__ w1p,
                                                       const float* __restrict__ b1,
                                                       const int* __restrict__ gstart,
                                                       float* __restrict__ gsum) {
    __shared__ float wsum[4][128];
    int tid = threadIdx.x;
    int lane = tid & 63, wave = tid >> 6;
    int quad = lane >> 4, l15 = lane & 15;
    int g = blockIdx.x;
    int nbase = blockIdx.y * 128;
    int ms = blockIdx.z;
    int r0 = gstart[g], r1 = gstart[g + 1];

    float b1v[8];
#pragma unroll
    for (int t = 0; t < 8; ++t) b1v[t] = b1[nbase + t * 16 + l15];

    const unsigned short* bbase = w1p + ((size_t)(blockIdx.y * 8) * 4 * 64 + lane) * 8;

    float gaccT[8];
#pragma unroll
    for (int t = 0; t < 8; ++t) gaccT[t] = 0.f;

    for (int mbase = r0 + ms * 64; mbase < r1; mbase += 64 * MSPLIT) {
        int m = mbase + wave * 16 + l15;
        int mc = m < N_NODES ? m : N_NODES - 1;      // clamp; invalid rows masked below
        const unsigned short* arow = h3b + (size_t)mc * 128 + quad * 8;
        bf16x8 afrag[4];
#pragma unroll
        for (int s = 0; s < 4; ++s)
            afrag[s] = *(const bf16x8*)(arow + s * 32);

        int rowbase = mbase + wave * 16 + quad * 4;  // this lane's C rows: rowbase+rg
#pragma unroll
        for (int t = 0; t < 8; ++t) {
            f32x4 acc = (f32x4){0.f, 0.f, 0.f, 0.f};
#pragma unroll
            for (int s = 0; s < 4; ++s) {
                bf16x8 bfrag = *(const bf16x8*)(bbase + (size_t)(t * 4 + s) * 64 * 8);
                acc = __builtin_amdgcn_mfma_f32_16x16x32_bf16(afrag[s], bfrag, acc, 0, 0, 0);
            }
#pragma unroll
            for (int rg = 0; rg < 4; ++rg) {
                float v = acc[rg] + b1v[t];
                v = v > 0.f ? v : 0.f;
                gaccT[t] += (rowbase + rg < r1) ? v : 0.f;
            }
        }
    }
    // sum the 4 quads (rows 0..15 of the wave strip) per column
#pragma unroll
    for (int t = 0; t < 8; ++t) {
        gaccT[t] += __shfl_xor(gaccT[t], 16, 64);
        gaccT[t] += __shfl_xor(gaccT[t], 32, 64);
    }
    if (quad == 0) {
#pragma unroll
        for (int t = 0; t < 8; ++t)
            wsum[wave][t * 16 + l15] = gaccT[t];
    }
    __syncthreads();
    if (tid < 128)
        gsum[((size_t)ms * N_GRAPHS + g) * D_H + nbase + tid] =
            wsum[0][tid] + wsum[1][tid] + wsum[2][tid] + wsum[3][tid];
}

// ---------------------------------------------------------------- final: mean + folded (512x16) projection

__global__ __launch_bounds__(256) void final_pool(const float* __restrict__ gsum,
                                                  const int* __restrict__ gcnt,
                                                  const float* __restrict__ wcomb,
                                                  const float* __restrict__ bcomb,
                                                  float* __restrict__ out) {
    int g = blockIdx.x;
    int tid = threadIdx.x;
    __shared__ float p[D_H];
    __shared__ float part[16][17];
    int c = gcnt[g]; if (c < 1) c = 1;
    float inv = 1.0f / (float)c;
#pragma unroll
    for (int h = 0; h < 2; ++h) {
        int i = tid + h * 256;
        float v = 0.f;
#pragma unroll
        for (int ms = 0; ms < MSPLIT; ++ms)
            v += gsum[((size_t)ms * N_GRAPHS + g) * D_H + i];
        p[i] = v * inv;
    }
    __syncthreads();
    int o = tid & 15, ch = tid >> 4;
    int k0 = ch * 32;
    float s = 0.f;
    for (int k = k0; k < k0 + 32; ++k)
        s += p[k] * wcomb[k * D_OUT + o];
    part[ch][o] = s;
    __syncthreads();
    if (tid < D_OUT) {
        float t = bcomb[tid];
        for (int ch2 = 0; ch2 < 16; ++ch2) t += part[ch2][tid];
        out[g * D_OUT + tid] = t;
    }
}

// ---------------------------------------------------------------- launch

extern "C" void kernel_launch(void* const* d_in, const int* in_sizes, int n_in,
                              void* d_out, int out_size, void* d_ws, size_t ws_size,
                              hipStream_t stream) {
    const float* x     = (const float*)d_in[0];
    const int*   eidx  = (const int*)d_in[1];   // [2, E]
    const int*   batch = (const int*)d_in[2];
    const float* w1    = (const float*)d_in[3];
    const float* b1    = (const float*)d_in[4];
    const float* w2    = (const float*)d_in[5];
    const float* b2    = (const float*)d_in[6];
    const float* wc    = (const float*)d_in[7];
    const float* bc    = (const float*)d_in[8];
    float* out = (float*)d_out;
    const int* row = eidx;
    const int* col = eidx + N_EDGES;

    char* p = (char*)d_ws;
    auto alloc = [&](size_t bytes) { char* q = p; p += (bytes + 255) & ~(size_t)255; return q; };
    // zero-init region: only bucket_cnt
    char* zbase = p;
    int*   bucket_cnt = (int*)alloc((size_t)NBUK * 4);
    size_t zbytes = (size_t)(p - zbase);
    float* gsum    = (float*)alloc((size_t)MSPLIT * N_GRAPHS * D_H * 4);
    int*   rowptr  = (int*)alloc((size_t)(N_NODES + 1) * 4);
    int*   gcnt    = (int*)alloc((size_t)N_GRAPHS * 4);
    int*   gstart  = (int*)alloc((size_t)(N_GRAPHS + 1) * 4);
    float* invdeg  = (float*)alloc((size_t)N_NODES * 4);
    float* wcomb   = (float*)alloc((size_t)D_H * D_OUT * 4);
    float* bcomb   = (float*)alloc((size_t)D_OUT * 4);
    unsigned* edge_buf = (unsigned*)alloc((size_t)NBUK * BUK_CAP * 4);
    unsigned short* csr_col = (unsigned short*)alloc((size_t)N_EDGES * 2);
    unsigned short* xf  = (unsigned short*)alloc((size_t)(N_NODES + 1) * 64 * 2);  // fp8x2 + zero row
    unsigned short* h0f = (unsigned short*)alloc((size_t)(N_NODES + 1) * 64 * 2);  // fp8x2 + zero row
    unsigned short* h1f = (unsigned short*)alloc((size_t)(N_NODES + 1) * 64 * 2);  // fp8x2 + zero row
    unsigned* h3b  = (unsigned*)alloc((size_t)N_NODES * 64 * 4);                   // bf16x2 node-major
    unsigned short* w1p = (unsigned short*)alloc((size_t)D_IN * D_H * 2);

    (void)hipMemsetAsync(zbase, 0, zbytes, stream);

    prep<<<12790, 256, 0, stream>>>(x, xf, w1, w1p, w2, wc, b2, bc, batch,
                                    wcomb, bcomb, gcnt, gstart, h0f, h1f);

    partition_edges<<<P1_BLOCKS, 512, 0, stream>>>(row, col, bucket_cnt, edge_buf);
    finalize_csr<<<NBUK, 512, 0, stream>>>(edge_buf, bucket_cnt, rowptr, invdeg, csr_col);

    int pgrid = (N_NODES + 31) / 32;   // 8 rows/wave, 4 waves/block
    propagate_fp8<<<pgrid, 256, 0, stream>>>(xf,  h0f, nullptr, 0, 8.0f,
                                             rowptr, csr_col, invdeg);
    propagate_fp8<<<pgrid, 256, 0, stream>>>(h0f, h1f, nullptr, 0, 8.0f,
                                             rowptr, csr_col, invdeg);
    propagate_fp8<<<pgrid, 256, 0, stream>>>(h1f, nullptr, h3b, 1, 1.0f / 64.0f,
                                             rowptr, csr_col, invdeg);

    dim3 ggrid(N_GRAPHS, D_H / 128, MSPLIT);
    gemm_graph_pool<<<ggrid, 256, 0, stream>>>((const unsigned short*)h3b, w1p, b1,
                                               gstart, gsum);
    final_pool<<<N_GRAPHS, 256, 0, stream>>>(gsum, gcnt, wcomb, bcomb, out);
}